// Round 15
// baseline (67.874 us; speedup 1.0000x reference)
//
#include <hip/hip_runtime.h>

#define NB 8
#define TAPS 5

// antireflect column fetch
__device__ __forceinline__ float ldc(const float* __restrict__ row, int j, int N) {
    if ((unsigned)j < (unsigned)N) return row[j];
    const int e  = (j < 0) ? 0 : (N - 1);
    const int rr = (j < 0) ? -j : (2 * (N - 1) - j);
    return 2.f * row[e] - row[rr];
}
// antireflect row+column fetch
__device__ __forceinline__ float ldrc(const float* __restrict__ plane, int m, int j, int N) {
    if ((unsigned)m < (unsigned)N) return ldc(plane + (size_t)m * N, j, N);
    const int e  = (m < 0) ? 0 : (N - 1);
    const int rm = (m < 0) ? -m : (2 * (N - 1) - m);
    return 2.f * ldc(plane + (size_t)e * N, j, N) - ldc(plane + (size_t)rm * N, j, N);
}
__device__ __forceinline__ void fma4(float4& a, float c, const float4& v) {
    a.x += c * v.x; a.y += c * v.y; a.z += c * v.z; a.w += c * v.w;
}
// async global->LDS, 16B per lane, no VGPR round trip
__device__ __forceinline__ void gl_lds16(const float* g, float* l) {
    __builtin_amdgcn_global_load_lds(
        (const __attribute__((address_space(1))) void*)g,
        (__attribute__((address_space(3))) void*)l, 16, 0, 0);
}

// ================= level 1/2 kernel: verified R14 structure =================
template<int TH, int TW>
__global__ __launch_bounds__(256)
void idwt_glds(const float* __restrict__ Ass, const float* __restrict__ Asd,
               const float* __restrict__ Ads, const float* __restrict__ Add,
               const float* __restrict__ h, const float* __restrict__ g,
               float* __restrict__ out, int N, int gx, int gy) {
    constexpr int THc = TH / 2;
    constexpr int SW  = TW / 2 + 8;
    constexpr int SW4 = SW / 4;
    constexpr int RH  = THc + 4;
    constexpr int NPP = RH * SW4;
    constexpr int NT  = 4 * NPP;
    constexpr int KMAX = (NT + 255) / 256;
    __shared__ float Ain[4][RH][SW];
    __shared__ float Sh[TH][SW];
    __shared__ float Dh[TH][SW];

    const int nwg = gridDim.x;
    const int hw  = blockIdx.x;
    const int lb  = (nwg & 7) ? hw : ((hw & 7) * (nwg >> 3) + (hw >> 3));
    const int strip = lb % gx;
    const int rowb  = (lb / gx) % gy;
    const int b     = lb / (gx * gy);

    const int r0 = rowb * TH;
    const int w0 = strip * TW;
    const int n0 = r0 >> 1, c0 = w0 >> 1;
    const int m0 = n0 - 2,  j0 = c0 - 4;
    const int tid = threadIdx.x;

    float hk[2][TAPS], gk[2][TAPS];
#pragma unroll
    for (int t = 0; t < TAPS; ++t) {
        hk[0][t] = h[8 - 2 * t]; hk[1][t] = h[9 - 2 * t];
        gk[0][t] = g[8 - 2 * t]; gk[1][t] = g[9 - 2 * t];
    }

    const size_t plane = (size_t)N * N;
    const float* P0 = Ass + (size_t)b * plane;
    const float* P1 = Asd + (size_t)b * plane;
    const float* P2 = Ads + (size_t)b * plane;
    const float* P3 = Add + (size_t)b * plane;
    float* lds0 = &Ain[0][0][0];

    const bool interior = (m0 >= 0) && (m0 + RH <= N) && (j0 >= 0) && (j0 + SW <= N);
    if (interior) {
#pragma unroll
        for (int k = 0; k < KMAX; ++k) {
            const int e = k * 256 + tid;
            if (e < NT) {
                const int q  = e / NPP;
                const int rm = e - q * NPP;
                const int r  = rm / SW4;
                const int fc = rm - r * SW4;
                const float* p = P0;
                if (q == 1) p = P1; else if (q == 2) p = P2; else if (q == 3) p = P3;
                gl_lds16(p + (size_t)(m0 + r) * N + j0 + 4 * fc, lds0 + 4 * e);
            }
        }
    } else {
        for (int e = tid; e < 4 * RH * SW; e += 256) {
            const int q  = e / (RH * SW);
            const int rm = e - q * (RH * SW);
            const int r  = rm / SW;
            const int kk = rm - r * SW;
            const float* p = P0;
            if (q == 1) p = P1; else if (q == 2) p = P2; else if (q == 3) p = P3;
            lds0[e] = ldrc(p, m0 + r, j0 + kk, N);
        }
    }
    __syncthreads();

    for (int e = tid; e < THc * SW4; e += 256) {
        const int nl = e / SW4;
        const int fc = (e - nl * SW4) * 4;
        float4 s0 = {0,0,0,0}, s1 = {0,0,0,0}, d0 = {0,0,0,0}, d1 = {0,0,0,0};
#pragma unroll
        for (int t = 0; t < TAPS; ++t) {
            const float4 va = *reinterpret_cast<const float4*>(&Ain[0][nl + t][fc]);
            const float4 vb = *reinterpret_cast<const float4*>(&Ain[1][nl + t][fc]);
            const float4 vc = *reinterpret_cast<const float4*>(&Ain[2][nl + t][fc]);
            const float4 vd = *reinterpret_cast<const float4*>(&Ain[3][nl + t][fc]);
            fma4(s0, hk[0][t], va); fma4(s0, gk[0][t], vb);
            fma4(s1, hk[1][t], va); fma4(s1, gk[1][t], vb);
            fma4(d0, hk[0][t], vc); fma4(d0, gk[0][t], vd);
            fma4(d1, hk[1][t], vc); fma4(d1, gk[1][t], vd);
        }
        *reinterpret_cast<float4*>(&Sh[2 * nl][fc])     = s0;
        *reinterpret_cast<float4*>(&Sh[2 * nl + 1][fc]) = s1;
        *reinterpret_cast<float4*>(&Dh[2 * nl][fc])     = d0;
        *reinterpret_cast<float4*>(&Dh[2 * nl + 1][fc]) = d1;
    }
    __syncthreads();

    const int M = 2 * N;
    constexpr int KW = TW / 8;
    for (int e = tid; e < TH * KW; e += 256) {
        const int r = e / KW;
        const int u = e - r * KW;
        float sv[12], dv[12];
        *reinterpret_cast<float4*>(&sv[0]) = *reinterpret_cast<const float4*>(&Sh[r][4 * u]);
        *reinterpret_cast<float4*>(&sv[4]) = *reinterpret_cast<const float4*>(&Sh[r][4 * u + 4]);
        *reinterpret_cast<float4*>(&sv[8]) = *reinterpret_cast<const float4*>(&Sh[r][4 * u + 8]);
        *reinterpret_cast<float4*>(&dv[0]) = *reinterpret_cast<const float4*>(&Dh[r][4 * u]);
        *reinterpret_cast<float4*>(&dv[4]) = *reinterpret_cast<const float4*>(&Dh[r][4 * u + 4]);
        *reinterpret_cast<float4*>(&dv[8]) = *reinterpret_cast<const float4*>(&Dh[r][4 * u + 8]);
        float o[8];
#pragma unroll
        for (int cc = 0; cc < 4; ++cc) {
            float o0 = 0.f, o1 = 0.f;
#pragma unroll
            for (int t = 0; t < TAPS; ++t) {
                const float sx = sv[cc + t + 2], dx = dv[cc + t + 2];
                o0 += hk[0][t] * sx + gk[0][t] * dx;
                o1 += hk[1][t] * sx + gk[1][t] * dx;
            }
            o[2 * cc] = o0; o[2 * cc + 1] = o1;
        }
        float* dst = out + ((size_t)b * M + (r0 + r)) * M + w0 + 8 * u;
        *reinterpret_cast<float4*>(dst)     = make_float4(o[0], o[1], o[2], o[3]);
        *reinterpret_cast<float4*>(dst + 4) = make_float4(o[4], o[5], o[6], o[7]);
    }
}

// ========== level 0: persistent block, double-buffered Ain, counted vmcnt ==========
// Block owns G consecutive row-tiles of one column strip. Prefetch of tile t+1
// stays in flight across raw s_barriers (never vmcnt(0) in the loop).
template<int TH, int TW, int G>
__global__ __launch_bounds__(256)
void idwt_pipe0(const float* __restrict__ Ass, const float* __restrict__ Asd,
                const float* __restrict__ Ads, const float* __restrict__ Add,
                const float* __restrict__ h, const float* __restrict__ g,
                float* __restrict__ out, int N, int gx, int gyg) {
    constexpr int THc = TH / 2;
    constexpr int SW  = TW / 2 + 8;
    constexpr int SW4 = SW / 4;
    constexpr int RH  = THc + 4;
    constexpr int NPP = RH * SW4;
    constexpr int NT  = 4 * NPP;
    constexpr int KMAX = (NT + 255) / 256;
    __shared__ float buf[2][4][RH][SW];
    __shared__ float Sh[TH][SW];
    __shared__ float Dh[TH][SW];

    const int nwg = gridDim.x;
    const int hw  = blockIdx.x;
    const int lb  = (nwg & 7) ? hw : ((hw & 7) * (nwg >> 3) + (hw >> 3));
    const int strip = lb % gx;
    const int grp   = (lb / gx) % gyg;
    const int b     = lb / (gx * gyg);
    const int rb0   = grp * G;               // first tile index
    const int w0 = strip * TW;
    const int c0 = w0 >> 1;
    const int j0 = c0 - 4;
    const int tid = threadIdx.x;
    const bool colInt = (j0 >= 0) && (j0 + SW <= N);

    float hk[2][TAPS], gk[2][TAPS];
#pragma unroll
    for (int t = 0; t < TAPS; ++t) {
        hk[0][t] = h[8 - 2 * t]; hk[1][t] = h[9 - 2 * t];
        gk[0][t] = g[8 - 2 * t]; gk[1][t] = g[9 - 2 * t];
    }

    const size_t plane = (size_t)N * N;
    const float* P0 = Ass + (size_t)b * plane;
    const float* P1 = Asd + (size_t)b * plane;
    const float* P2 = Ads + (size_t)b * plane;
    const float* P3 = Add + (size_t)b * plane;

    // stage tile tt into buffer sl; returns true if scalar (ds_write) path used
    auto STAGE = [&](int tt, int sl) -> bool {
        const int m0l = tt * THc - 2;
        float* l = &buf[sl][0][0][0];
        const bool inter = colInt && (m0l >= 0) && (m0l + RH <= N);
        if (inter) {
#pragma unroll
            for (int k = 0; k < KMAX; ++k) {
                const int e = k * 256 + tid;
                if (e < NT) {
                    const int q  = e / NPP;
                    const int rm = e - q * NPP;
                    const int r  = rm / SW4;
                    const int fc = rm - r * SW4;
                    const float* p = P0;
                    if (q == 1) p = P1; else if (q == 2) p = P2; else if (q == 3) p = P3;
                    gl_lds16(p + (size_t)(m0l + r) * N + j0 + 4 * fc, l + 4 * e);
                }
            }
        } else {
            for (int e = tid; e < 4 * RH * SW; e += 256) {
                const int q  = e / (RH * SW);
                const int rm = e - q * (RH * SW);
                const int r  = rm / SW;
                const int kk = rm - r * SW;
                const float* p = P0;
                if (q == 1) p = P1; else if (q == 2) p = P2; else if (q == 3) p = P3;
                l[e] = ldrc(p, m0l + r, j0 + kk, N);
            }
        }
        return !inter;
    };

    const int M = 2 * N;
    constexpr int KW = TW / 8;

    bool curScalar = STAGE(rb0, 0);
    for (int t = 0; t < G; ++t) {
        const int sl = t & 1;
        bool nextScalar = false;
        if (t + 1 < G) {
            nextScalar = STAGE(rb0 + t + 1, sl ^ 1);
            if (curScalar) asm volatile("s_waitcnt vmcnt(4) lgkmcnt(0)" ::: "memory");
            else           asm volatile("s_waitcnt vmcnt(4)" ::: "memory");
        } else {
            asm volatile("s_waitcnt vmcnt(0) lgkmcnt(0)" ::: "memory");
        }
        __builtin_amdgcn_sched_barrier(0);
        __builtin_amdgcn_s_barrier();
        __builtin_amdgcn_sched_barrier(0);

        // phase 1: vertical synthesis from buf[sl]
        for (int e = tid; e < THc * SW4; e += 256) {
            const int nl = e / SW4;
            const int fc = (e - nl * SW4) * 4;
            float4 s0 = {0,0,0,0}, s1 = {0,0,0,0}, d0 = {0,0,0,0}, d1 = {0,0,0,0};
#pragma unroll
            for (int tt = 0; tt < TAPS; ++tt) {
                const float4 va = *reinterpret_cast<const float4*>(&buf[sl][0][nl + tt][fc]);
                const float4 vb = *reinterpret_cast<const float4*>(&buf[sl][1][nl + tt][fc]);
                const float4 vc = *reinterpret_cast<const float4*>(&buf[sl][2][nl + tt][fc]);
                const float4 vd = *reinterpret_cast<const float4*>(&buf[sl][3][nl + tt][fc]);
                fma4(s0, hk[0][tt], va); fma4(s0, gk[0][tt], vb);
                fma4(s1, hk[1][tt], va); fma4(s1, gk[1][tt], vb);
                fma4(d0, hk[0][tt], vc); fma4(d0, gk[0][tt], vd);
                fma4(d1, hk[1][tt], vc); fma4(d1, gk[1][tt], vd);
            }
            *reinterpret_cast<float4*>(&Sh[2 * nl][fc])     = s0;
            *reinterpret_cast<float4*>(&Sh[2 * nl + 1][fc]) = s1;
            *reinterpret_cast<float4*>(&Dh[2 * nl][fc])     = d0;
            *reinterpret_cast<float4*>(&Dh[2 * nl + 1][fc]) = d1;
        }
        asm volatile("s_waitcnt lgkmcnt(0)" ::: "memory");
        __builtin_amdgcn_sched_barrier(0);
        __builtin_amdgcn_s_barrier();
        __builtin_amdgcn_sched_barrier(0);

        // phase 2: horizontal synthesis + stores
        const int r0 = (rb0 + t) * TH;
        for (int e = tid; e < TH * KW; e += 256) {
            const int r = e / KW;
            const int u = e - r * KW;
            float sv[12], dv[12];
            *reinterpret_cast<float4*>(&sv[0]) = *reinterpret_cast<const float4*>(&Sh[r][4 * u]);
            *reinterpret_cast<float4*>(&sv[4]) = *reinterpret_cast<const float4*>(&Sh[r][4 * u + 4]);
            *reinterpret_cast<float4*>(&sv[8]) = *reinterpret_cast<const float4*>(&Sh[r][4 * u + 8]);
            *reinterpret_cast<float4*>(&dv[0]) = *reinterpret_cast<const float4*>(&Dh[r][4 * u]);
            *reinterpret_cast<float4*>(&dv[4]) = *reinterpret_cast<const float4*>(&Dh[r][4 * u + 4]);
            *reinterpret_cast<float4*>(&dv[8]) = *reinterpret_cast<const float4*>(&Dh[r][4 * u + 8]);
            float o[8];
#pragma unroll
            for (int cc = 0; cc < 4; ++cc) {
                float o0 = 0.f, o1 = 0.f;
#pragma unroll
                for (int tt = 0; tt < TAPS; ++tt) {
                    const float sx = sv[cc + tt + 2], dx = dv[cc + tt + 2];
                    o0 += hk[0][tt] * sx + gk[0][tt] * dx;
                    o1 += hk[1][tt] * sx + gk[1][tt] * dx;
                }
                o[2 * cc] = o0; o[2 * cc + 1] = o1;
            }
            float* dst = out + ((size_t)b * M + (r0 + r)) * M + w0 + 8 * u;
            *reinterpret_cast<float4*>(dst)     = make_float4(o[0], o[1], o[2], o[3]);
            *reinterpret_cast<float4*>(dst + 4) = make_float4(o[4], o[5], o[6], o[7]);
        }
        curScalar = nextScalar;
    }
}

extern "C" void kernel_launch(void* const* d_in, const int* in_sizes, int n_in,
                              void* d_out, int out_size, void* d_ws, size_t ws_size,
                              hipStream_t stream) {
    const float* ss = (const float*)d_in[0];
    const float* sd[3] = {(const float*)d_in[1], (const float*)d_in[2], (const float*)d_in[3]};
    const float* ds[3] = {(const float*)d_in[4], (const float*)d_in[5], (const float*)d_in[6]};
    const float* dd[3] = {(const float*)d_in[7], (const float*)d_in[8], (const float*)d_in[9]};
    const float* h = (const float*)d_in[10];
    const float* g = (const float*)d_in[11];
    float* out = (float*)d_out;

    char* ws = (char*)d_ws;
    float* I0 = (float*)ws;                        // level-2 output (2 MiB)
    float* I1 = (float*)(ws + ((size_t)2 << 20));  // level-1 output (8 MiB)

    // level 2: 128 -> 256 (verified R14 kernel)
    {
        const int N = 128, gx = 256 / 32, gy = 256 / 16;
        idwt_glds<16, 32><<<gx * gy * NB, 256, 0, stream>>>(
            ss, sd[2], ds[2], dd[2], h, g, I0, N, gx, gy);
    }
    // level 1: 256 -> 512 (verified R14 kernel)
    {
        const int N = 256, gx = 512 / 64, gy = 512 / 32;
        idwt_glds<32, 64><<<gx * gy * NB, 256, 0, stream>>>(
            I0, sd[1], ds[1], dd[1], h, g, I1, N, gx, gy);
    }
    // level 0: 512 -> 1024 (pipelined persistent blocks, G=4 tiles each)
    {
        const int N = 512, gx = 1024 / 64, gy = 1024 / 32, G = 4;
        idwt_pipe0<32, 64, 4><<<gx * (gy / G) * NB, 256, 0, stream>>>(
            I1, sd[0], ds[0], dd[0], h, g, out, N, gx, gy / G);
    }
}

// Round 16
// 45.770 us; speedup vs baseline: 1.4829x; 1.4829x over previous
//
#include <hip/hip_runtime.h>

#define TAPS 5

// antireflect fetch from a global plane (valid for |overhang| <= N-2)
__device__ __forceinline__ float ldcg(const float* __restrict__ row, int j, int N) {
    if ((unsigned)j < (unsigned)N) return row[j];
    const int e = (j < 0) ? 0 : N - 1;
    const int r = (j < 0) ? -j : 2 * (N - 1) - j;
    return 2.f * row[e] - row[r];
}
__device__ __forceinline__ float ldrc(const float* __restrict__ p, int m, int j, int N) {
    if ((unsigned)m < (unsigned)N) return ldcg(p + (size_t)m * N, j, N);
    const int e = (m < 0) ? 0 : N - 1;
    const int r = (m < 0) ? -m : 2 * (N - 1) - m;
    return 2.f * ldcg(p + (size_t)e * N, j, N) - ldcg(p + (size_t)r * N, j, N);
}
__device__ __forceinline__ void fma4(float4& a, float c, const float4& v) {
    a.x += c * v.x; a.y += c * v.y; a.z += c * v.z; a.w += c * v.w;
}
__device__ __forceinline__ float4 ldsf4(const float* p) { return *reinterpret_cast<const float4*>(p); }
__device__ __forceinline__ void stsf4(float* p, const float4& v) { *reinterpret_cast<float4*>(p) = v; }

// LDS layout (floats): ST 0..4320 | SD 4320..9440 | I0 9440..10016 | I1 10016..11456
#define OFF_SD 4320
#define OFF_I0 9440
#define OFF_I1 10016
#define SM_FLOATS 11456

// One block = one 64x64 output tile; all 3 IDWT levels fused through LDS.
__global__ __launch_bounds__(256)
void idwt3(const float* __restrict__ ss,
           const float* __restrict__ sd0, const float* __restrict__ sd1, const float* __restrict__ sd2,
           const float* __restrict__ ds0, const float* __restrict__ ds1, const float* __restrict__ ds2,
           const float* __restrict__ dd0, const float* __restrict__ dd1, const float* __restrict__ dd2,
           const float* __restrict__ h, const float* __restrict__ g_,
           float* __restrict__ out) {
    extern __shared__ float sm[];
    float* ST = sm;
    float* SD = sm + OFF_SD;
    float* I0 = sm + OFF_I0;   // [24][24], rows R0/4-4.., cols W0/4-4..
    float* I1 = sm + OFF_I1;   // [36][40] (36 cols used), rows R0/2-2.., cols W0/2-2..

    const int hw = blockIdx.x;
    const int lb = (hw & 7) * 256 + (hw >> 3);   // XCD swizzle: XCD i -> batch i
    const int b  = lb >> 8;
    const int tile = lb & 255;
    const int tr = tile >> 4, tc = tile & 15;
    const int R0 = tr * 64, W0 = tc * 64;
    const int tid = threadIdx.x;

    float hk0[TAPS], hk1[TAPS], gk0[TAPS], gk1[TAPS];
#pragma unroll
    for (int t = 0; t < TAPS; ++t) {
        hk0[t] = h[8 - 2 * t];  hk1[t] = h[9 - 2 * t];
        gk0[t] = g_[8 - 2 * t]; gk1[t] = g_[9 - 2 * t];
    }

    // ================= LEVEL 2 (N=128) =================
    {   // stage A2: 4 planes [16][16]; rows R0/8-4.., cols W0/8-4..
        const int r0g = (R0 >> 3) - 4, c0g = (W0 >> 3) - 4;
        const float* P[4] = {ss + (size_t)b * 16384, sd2 + (size_t)b * 16384,
                             ds2 + (size_t)b * 16384, dd2 + (size_t)b * 16384};
        for (int e = tid; e < 1024; e += 256) {
            const int q = e >> 8, rm = e & 255;
            ST[e] = ldrc(P[q], r0g + (rm >> 4), c0g + (rm & 15), 128);
        }
    }
    __syncthreads();
    {   // vert2 -> S2 [24][16] @SD, D2 @SD+384 (rows in I0 space, row0 = R0/4-4)
        const int lo = max((R0 >> 3) - 2, 0), hi = min((R0 >> 3) + 10, 128);
        const int a2r0 = (R0 >> 3) - 4;
        const int cnt = (hi - lo) * 4;
        for (int e = tid; e < cnt; e += 256) {
            const int i = e >> 2, fc = (e & 3) * 4;
            const int n = lo + i;
            float4 s0{0,0,0,0}, s1{0,0,0,0}, d0{0,0,0,0}, d1{0,0,0,0};
#pragma unroll
            for (int t = 0; t < TAPS; ++t) {
                const int rr = (n - 2 + t - a2r0) * 16 + fc;
                const float4 va = ldsf4(ST + rr);
                const float4 vb = ldsf4(ST + 256 + rr);
                const float4 vc = ldsf4(ST + 512 + rr);
                const float4 vd = ldsf4(ST + 768 + rr);
                fma4(s0, hk0[t], va); fma4(s0, gk0[t], vb);
                fma4(s1, hk1[t], va); fma4(s1, gk1[t], vb);
                fma4(d0, hk0[t], vc); fma4(d0, gk0[t], vd);
                fma4(d1, hk1[t], vc); fma4(d1, gk1[t], vd);
            }
            const int ri = 2 * (n - ((R0 >> 3) - 2));
            stsf4(SD + ri * 16 + fc, s0); stsf4(SD + (ri + 1) * 16 + fc, s1);
            stsf4(SD + 384 + ri * 16 + fc, d0); stsf4(SD + 384 + (ri + 1) * 16 + fc, d1);
        }
    }
    __syncthreads();
    // horiz2 -> I0 [24][24]; overlap: stage A1 (3 planes [22][24]) into regs
    float rA1[7];
    {
        const int a1r0 = (R0 >> 2) - 3, a1c0 = (W0 >> 2) - 4;
        const float* P[3] = {sd1 + (size_t)b * 65536, ds1 + (size_t)b * 65536, dd1 + (size_t)b * 65536};
#pragma unroll
        for (int k = 0; k < 7; ++k) {
            const int e = tid + 256 * k;
            if (e < 1584) {
                const int q = e / 528, rm = e - q * 528;
                rA1[k] = ldrc(P[q], a1r0 + rm / 24, a1c0 + rm % 24, 256);
            }
        }
    }
    {
        const int i0r0 = (R0 >> 2) - 4;
        const int riLo = max(0, -i0r0), riHi = min(24, 256 - i0r0);
        const int pcLo = max(0, -((W0 >> 3) - 2)), pcHi = min(12, 128 - ((W0 >> 3) - 2));
        const int np = pcHi - pcLo, cnt = (riHi - riLo) * np;
        for (int e = tid; e < cnt; e += 256) {
            const int ri = riLo + e / np, pc = pcLo + e % np;
            float o0 = 0.f, o1 = 0.f;
#pragma unroll
            for (int t = 0; t < TAPS; ++t) {
                const float sv = SD[ri * 16 + pc + t];
                const float dv = SD[384 + ri * 16 + pc + t];
                o0 += hk0[t] * sv + gk0[t] * dv;
                o1 += hk1[t] * sv + gk1[t] * dv;
            }
            I0[ri * 24 + 2 * pc] = o0; I0[ri * 24 + 2 * pc + 1] = o1;
        }
    }
#pragma unroll
    for (int k = 0; k < 7; ++k) {   // commit A1 regs -> ST (A2 dead)
        const int e = tid + 256 * k;
        if (e < 1584) ST[e] = rA1[k];
    }
    __syncthreads();
    {   // I0 col fixup (virtual cols from true cols), true rows only
        const int i0r0 = (R0 >> 2) - 4, i0c0 = (W0 >> 2) - 4;
        const int riLo = max(0, -i0r0), riHi = min(24, 256 - i0r0), nr = riHi - riLo;
        const int zL = max(0, -i0c0), eR = min(24, 256 - i0c0);
        if (zL > 0) for (int e = tid; e < nr * zL; e += 256) {
            const int ri = riLo + e / zL, vc = e % zL;
            I0[ri * 24 + vc] = 2.f * I0[ri * 24 + zL] - I0[ri * 24 + 2 * zL - vc];
        }
        if (eR < 24) { const int nv = 24 - eR;
            for (int e = tid; e < nr * nv; e += 256) {
                const int ri = riLo + e / nv, vc = eR + e % nv;
                I0[ri * 24 + vc] = 2.f * I0[ri * 24 + eR - 1] - I0[ri * 24 + 2 * (eR - 1) - vc];
            } }
    }
    __syncthreads();
    {   // I0 row fixup (all 24 cols)
        const int i0r0 = (R0 >> 2) - 4;
        const int zT = max(0, -i0r0), eB = min(24, 256 - i0r0);
        if (zT > 0) for (int e = tid; e < zT * 24; e += 256) {
            const int vr = e / 24, c = e % 24;
            I0[vr * 24 + c] = 2.f * I0[zT * 24 + c] - I0[(2 * zT - vr) * 24 + c];
        }
        if (eB < 24) { const int nv = 24 - eB;
            for (int e = tid; e < nv * 24; e += 256) {
                const int vr = eB + e / 24, c = e % 24;
                I0[vr * 24 + c] = 2.f * I0[(eB - 1) * 24 + c] - I0[(2 * (eB - 1) - vr) * 24 + c];
            } }
    }
    __syncthreads();

    // ================= LEVEL 1 (N=256) =================
    {   // vert1 -> S1 [36][24] @SD, D1 @SD+864 (rows in I1 space, row0 = R0/2-2)
        const int lo = max((R0 >> 2) - 1, 0), hi = min((R0 >> 2) + 17, 256);
        const int i0r0 = (R0 >> 2) - 4, a1r0 = (R0 >> 2) - 3;
        const int cnt = (hi - lo) * 6;
        for (int e = tid; e < cnt; e += 256) {
            const int i = e / 6, fc = (e % 6) * 4;
            const int n = lo + i;
            float4 s0{0,0,0,0}, s1{0,0,0,0}, d0{0,0,0,0}, d1{0,0,0,0};
#pragma unroll
            for (int t = 0; t < TAPS; ++t) {
                const int m = n - 2 + t;
                const float4 va = ldsf4(I0 + (m - i0r0) * 24 + fc);
                const int ar = (m - a1r0) * 24 + fc;
                const float4 vb = ldsf4(ST + ar);
                const float4 vc = ldsf4(ST + 528 + ar);
                const float4 vd = ldsf4(ST + 1056 + ar);
                fma4(s0, hk0[t], va); fma4(s0, gk0[t], vb);
                fma4(s1, hk1[t], va); fma4(s1, gk1[t], vb);
                fma4(d0, hk0[t], vc); fma4(d0, gk0[t], vd);
                fma4(d1, hk1[t], vc); fma4(d1, gk1[t], vd);
            }
            const int ri = 2 * (n - ((R0 >> 2) - 1));
            stsf4(SD + ri * 24 + fc, s0); stsf4(SD + (ri + 1) * 24 + fc, s1);
            stsf4(SD + 864 + ri * 24 + fc, d0); stsf4(SD + 864 + (ri + 1) * 24 + fc, d1);
        }
    }
    __syncthreads();
    // horiz1 -> I1 [36][40]; overlap: stage A0 (3 planes [36][40], 36 cols) into regs
    float rA0[16];
    {
        const int a0r0 = (R0 >> 1) - 2, a0c0 = (W0 >> 1) - 2;
        const float* P[3] = {sd0 + (size_t)b * 262144, ds0 + (size_t)b * 262144, dd0 + (size_t)b * 262144};
#pragma unroll
        for (int k = 0; k < 16; ++k) {
            const int e = tid + 256 * k;
            if (e < 3888) {
                const int q = e / 1296, rm = e - q * 1296;
                rA0[k] = ldrc(P[q], a0r0 + rm / 36, a0c0 + rm % 36, 512);
            }
        }
    }
    {
        const int i1r0 = (R0 >> 1) - 2;
        const int riLo = max(0, -i1r0), riHi = min(36, 512 - i1r0);
        const int pcLo = max(0, -((W0 >> 2) - 1)), pcHi = min(18, 256 - ((W0 >> 2) - 1));
        const int np = pcHi - pcLo, cnt = (riHi - riLo) * np;
        for (int e = tid; e < cnt; e += 256) {
            const int ri = riLo + e / np, pc = pcLo + e % np;
            float o0 = 0.f, o1 = 0.f;
#pragma unroll
            for (int t = 0; t < TAPS; ++t) {
                const float sv = SD[ri * 24 + pc + 1 + t];
                const float dv = SD[864 + ri * 24 + pc + 1 + t];
                o0 += hk0[t] * sv + gk0[t] * dv;
                o1 += hk1[t] * sv + gk1[t] * dv;
            }
            I1[ri * 40 + 2 * pc] = o0; I1[ri * 40 + 2 * pc + 1] = o1;
        }
    }
#pragma unroll
    for (int k = 0; k < 16; ++k) {  // commit A0 regs -> ST (A1 dead); stride 40
        const int e = tid + 256 * k;
        if (e < 3888) {
            const int q = e / 1296, rm = e - q * 1296;
            ST[q * 1440 + (rm / 36) * 40 + rm % 36] = rA0[k];
        }
    }
    __syncthreads();
    {   // I1 col fixup
        const int i1r0 = (R0 >> 1) - 2, i1c0 = (W0 >> 1) - 2;
        const int riLo = max(0, -i1r0), riHi = min(36, 512 - i1r0), nr = riHi - riLo;
        const int zL = max(0, -i1c0), eR = min(36, 512 - i1c0);
        if (zL > 0) for (int e = tid; e < nr * zL; e += 256) {
            const int ri = riLo + e / zL, vc = e % zL;
            I1[ri * 40 + vc] = 2.f * I1[ri * 40 + zL] - I1[ri * 40 + 2 * zL - vc];
        }
        if (eR < 36) { const int nv = 36 - eR;
            for (int e = tid; e < nr * nv; e += 256) {
                const int ri = riLo + e / nv, vc = eR + e % nv;
                I1[ri * 40 + vc] = 2.f * I1[ri * 40 + eR - 1] - I1[ri * 40 + 2 * (eR - 1) - vc];
            } }
    }
    __syncthreads();
    {   // I1 row fixup (all 36 cols)
        const int i1r0 = (R0 >> 1) - 2;
        const int zT = max(0, -i1r0), eB = min(36, 512 - i1r0);
        if (zT > 0) for (int e = tid; e < zT * 36; e += 256) {
            const int vr = e / 36, c = e % 36;
            I1[vr * 40 + c] = 2.f * I1[zT * 40 + c] - I1[(2 * zT - vr) * 40 + c];
        }
        if (eB < 36) { const int nv = 36 - eB;
            for (int e = tid; e < nv * 36; e += 256) {
                const int vr = eB + e / 36, c = e % 36;
                I1[vr * 40 + c] = 2.f * I1[(eB - 1) * 40 + c] - I1[(2 * (eB - 1) - vr) * 40 + c];
            } }
    }
    __syncthreads();

    // ================= LEVEL 0 (N=512) =================
    {   // vert0 -> S0 [64][40] @SD, D0 @SD+2560; eval n = R0/2 + i, all true
        for (int e = tid; e < 288; e += 256) {
            const int i = e / 9, fc = (e % 9) * 4;
            float4 s0{0,0,0,0}, s1{0,0,0,0}, d0{0,0,0,0}, d1{0,0,0,0};
#pragma unroll
            for (int t = 0; t < TAPS; ++t) {
                const int rr = (i + t) * 40 + fc;
                const float4 va = ldsf4(I1 + rr);
                const float4 vb = ldsf4(ST + rr);
                const float4 vc = ldsf4(ST + 1440 + rr);
                const float4 vd = ldsf4(ST + 2880 + rr);
                fma4(s0, hk0[t], va); fma4(s0, gk0[t], vb);
                fma4(s1, hk1[t], va); fma4(s1, gk1[t], vb);
                fma4(d0, hk0[t], vc); fma4(d0, gk0[t], vd);
                fma4(d1, hk1[t], vc); fma4(d1, gk1[t], vd);
            }
            const int ri = 2 * i;
            stsf4(SD + ri * 40 + fc, s0); stsf4(SD + (ri + 1) * 40 + fc, s1);
            stsf4(SD + 2560 + ri * 40 + fc, d0); stsf4(SD + 2560 + (ri + 1) * 40 + fc, d1);
        }
    }
    __syncthreads();
    {   // horiz0: 64 rows x 8 chunks of 4 pairs; vectorized LDS reads + f4 stores
        for (int e = tid; e < 512; e += 256) {
            const int ri = e >> 3, u = e & 7;
            float sv[8], dv[8];
            *reinterpret_cast<float4*>(&sv[0]) = ldsf4(SD + ri * 40 + 4 * u);
            *reinterpret_cast<float4*>(&sv[4]) = ldsf4(SD + ri * 40 + 4 * u + 4);
            *reinterpret_cast<float4*>(&dv[0]) = ldsf4(SD + 2560 + ri * 40 + 4 * u);
            *reinterpret_cast<float4*>(&dv[4]) = ldsf4(SD + 2560 + ri * 40 + 4 * u + 4);
            float o[8];
#pragma unroll
            for (int j = 0; j < 4; ++j) {
                float o0 = 0.f, o1 = 0.f;
#pragma unroll
                for (int t = 0; t < TAPS; ++t) {
                    o0 += hk0[t] * sv[j + t] + gk0[t] * dv[j + t];
                    o1 += hk1[t] * sv[j + t] + gk1[t] * dv[j + t];
                }
                o[2 * j] = o0; o[2 * j + 1] = o1;
            }
            float* dst = out + ((size_t)(b * 1024 + R0 + ri)) * 1024 + W0 + 8 * u;
            *reinterpret_cast<float4*>(dst)     = make_float4(o[0], o[1], o[2], o[3]);
            *reinterpret_cast<float4*>(dst + 4) = make_float4(o[4], o[5], o[6], o[7]);
        }
    }
}

extern "C" void kernel_launch(void* const* d_in, const int* in_sizes, int n_in,
                              void* d_out, int out_size, void* d_ws, size_t ws_size,
                              hipStream_t stream) {
    const float* ss  = (const float*)d_in[0];
    const float* sd0 = (const float*)d_in[1];
    const float* sd1 = (const float*)d_in[2];
    const float* sd2 = (const float*)d_in[3];
    const float* ds0 = (const float*)d_in[4];
    const float* ds1 = (const float*)d_in[5];
    const float* ds2 = (const float*)d_in[6];
    const float* dd0 = (const float*)d_in[7];
    const float* dd1 = (const float*)d_in[8];
    const float* dd2 = (const float*)d_in[9];
    const float* h = (const float*)d_in[10];
    const float* g = (const float*)d_in[11];
    float* out = (float*)d_out;

    // one dispatch: 2048 blocks (8 batch x 16x16 tiles), 44.75 KB dynamic LDS
    idwt3<<<2048, 256, SM_FLOATS * 4, stream>>>(
        ss, sd0, sd1, sd2, ds0, ds1, ds2, dd0, dd1, dd2, h, g, out);
}

// Round 17
// 38.035 us; speedup vs baseline: 1.7845x; 1.2034x over previous
//
#include <hip/hip_runtime.h>

#define TAPS 5

// antireflect fetch from a global plane
__device__ __forceinline__ float ldcg(const float* __restrict__ row, int j, int N) {
    if ((unsigned)j < (unsigned)N) return row[j];
    const int e = (j < 0) ? 0 : N - 1;
    const int r = (j < 0) ? -j : 2 * (N - 1) - j;
    return 2.f * row[e] - row[r];
}
__device__ __forceinline__ float ldrc(const float* __restrict__ p, int m, int j, int N) {
    if ((unsigned)m < (unsigned)N) return ldcg(p + (size_t)m * N, j, N);
    const int e = (m < 0) ? 0 : N - 1;
    const int r = (m < 0) ? -m : 2 * (N - 1) - m;
    return 2.f * ldcg(p + (size_t)e * N, j, N) - ldcg(p + (size_t)r * N, j, N);
}
__device__ __forceinline__ void fma4(float4& a, float c, const float4& v) {
    a.x += c * v.x; a.y += c * v.y; a.z += c * v.z; a.w += c * v.w;
}
__device__ __forceinline__ float4 ldsf4(const float* p) { return *reinterpret_cast<const float4*>(p); }
__device__ __forceinline__ void stsf4(float* p, const float4& v) { *reinterpret_cast<float4*>(p) = v; }
__device__ __forceinline__ void gl_lds16(const float* g, float* l) {
    __builtin_amdgcn_global_load_lds(
        (const __attribute__((address_space(1))) void*)g,
        (__attribute__((address_space(3))) void*)l, 16, 0, 0);
}

// LDS floats: ST 0..4320 | SD 4320..9440 | I0 9440..10016 | I1 10016..11456
#define OFF_SD 4320
#define OFF_I0 9440
#define OFF_I1 10016
#define SM_FLOATS 11456

// One block = one 64x64 output tile; 3 IDWT levels fused in LDS.
// inner tiles (tr,tc in [1,14]): gl_lds16 staging, compile-time bounds, no fixups.
// A0 / I1 live on a 40-col "x-grid" with col0 = W0/2-4 (16B aligned); used cols x in [2,38).
__global__ __launch_bounds__(256)
void idwt3(const float* __restrict__ ss,
           const float* __restrict__ sd0, const float* __restrict__ sd1, const float* __restrict__ sd2,
           const float* __restrict__ ds0, const float* __restrict__ ds1, const float* __restrict__ ds2,
           const float* __restrict__ dd0, const float* __restrict__ dd1, const float* __restrict__ dd2,
           const float* __restrict__ h, const float* __restrict__ g_,
           float* __restrict__ out) {
    extern __shared__ float sm[];
    float* ST = sm;
    float* SD = sm + OFF_SD;
    float* I0 = sm + OFF_I0;   // [24][24], row0 = R0/4-4, col0 = W0/4-4
    float* I1 = sm + OFF_I1;   // [36][40], row0 = R0/2-2, x-grid col0 = W0/2-4

    const int hw = blockIdx.x;
    const int lb = (hw & 7) * 256 + (hw >> 3);   // XCD swizzle: XCD i -> batch i
    const int b  = lb >> 8;
    const int tile = lb & 255;
    const int tr = tile >> 4, tc = tile & 15;
    const int R0 = tr * 64, W0 = tc * 64;
    const int tid = threadIdx.x;

    float hk0[TAPS], hk1[TAPS], gk0[TAPS], gk1[TAPS];
#pragma unroll
    for (int t = 0; t < TAPS; ++t) {
        hk0[t] = h[8 - 2 * t];  hk1[t] = h[9 - 2 * t];
        gk0[t] = g_[8 - 2 * t]; gk1[t] = g_[9 - 2 * t];
    }

    const float* pss  = ss  + (size_t)b * 16384;
    const float* psd2 = sd2 + (size_t)b * 16384;
    const float* pds2 = ds2 + (size_t)b * 16384;
    const float* pdd2 = dd2 + (size_t)b * 16384;
    const float* psd1 = sd1 + (size_t)b * 65536;
    const float* pds1 = ds1 + (size_t)b * 65536;
    const float* pdd1 = dd1 + (size_t)b * 65536;
    const float* psd0 = sd0 + (size_t)b * 262144;
    const float* pds0 = ds0 + (size_t)b * 262144;
    const float* pdd0 = dd0 + (size_t)b * 262144;

    const bool inner = (tr >= 1) && (tr <= 14) && (tc >= 1) && (tc <= 14);

    if (inner) {
        // ======== FAST PATH (all windows in-bounds, no fixups) ========
        {   // A2: 4 planes [16][16], 256 f4, one gl_lds16/thread
            const int r0g = 8 * tr - 4, c0g = 8 * tc - 4;
            const int q = tid >> 6, rm = tid & 63, r = rm >> 2, c4 = rm & 3;
            const float* p = (q == 0) ? pss : (q == 1) ? psd2 : (q == 2) ? pds2 : pdd2;
            gl_lds16(p + (r0g + r) * 128 + c0g + 4 * c4, ST + 4 * tid);
        }
        __syncthreads();
        // vert2 -> S2 [24][16] @SD, D2 @SD+384
        if (tid < 48) {
            const int i = tid >> 2, fc = (tid & 3) * 4;
            float4 s0{0,0,0,0}, s1{0,0,0,0}, d0{0,0,0,0}, d1{0,0,0,0};
#pragma unroll
            for (int t = 0; t < TAPS; ++t) {
                const int rr = (i + t) * 16 + fc;
                const float4 va = ldsf4(ST + rr);
                const float4 vb = ldsf4(ST + 256 + rr);
                const float4 vc = ldsf4(ST + 512 + rr);
                const float4 vd = ldsf4(ST + 768 + rr);
                fma4(s0, hk0[t], va); fma4(s0, gk0[t], vb);
                fma4(s1, hk1[t], va); fma4(s1, gk1[t], vb);
                fma4(d0, hk0[t], vc); fma4(d0, gk0[t], vd);
                fma4(d1, hk1[t], vc); fma4(d1, gk1[t], vd);
            }
            const int ri = 2 * i;
            stsf4(SD + ri * 16 + fc, s0); stsf4(SD + (ri + 1) * 16 + fc, s1);
            stsf4(SD + 384 + ri * 16 + fc, d0); stsf4(SD + 384 + (ri + 1) * 16 + fc, d1);
        }
        __syncthreads();
        {   // issue A1: 3 planes [22][24], 396 f4 (overlaps horiz2)
            const int a1r0 = 16 * tr - 3, a1c0 = 16 * tc - 4;
#pragma unroll
            for (int k = 0; k < 2; ++k) {
                const int e = tid + 256 * k;
                if (e < 396) {
                    const int q = e / 132, rm = e - q * 132, r = rm / 6, c4 = rm - r * 6;
                    const float* p = (q == 0) ? psd1 : (q == 1) ? pds1 : pdd1;
                    gl_lds16(p + (a1r0 + r) * 256 + a1c0 + 4 * c4, ST + 4 * e);
                }
            }
        }
        // horiz2 -> I0 [24][24] (288 items, compile-time bounds)
        for (int e = tid; e < 288; e += 256) {
            const int ri = e / 12, pc = e - ri * 12;
            float o0 = 0.f, o1 = 0.f;
#pragma unroll
            for (int t = 0; t < TAPS; ++t) {
                const float sv = SD[ri * 16 + pc + t];
                const float dv = SD[384 + ri * 16 + pc + t];
                o0 += hk0[t] * sv + gk0[t] * dv;
                o1 += hk1[t] * sv + gk1[t] * dv;
            }
            I0[ri * 24 + 2 * pc] = o0; I0[ri * 24 + 2 * pc + 1] = o1;
        }
        __syncthreads();   // drains A1 loads
        // vert1 -> S1 [36][24] @SD, D1 @SD+864 (108 items)
        if (tid < 108) {
            const int i = tid / 6, fc = (tid - i * 6) * 4;
            float4 s0{0,0,0,0}, s1{0,0,0,0}, d0{0,0,0,0}, d1{0,0,0,0};
#pragma unroll
            for (int t = 0; t < TAPS; ++t) {
                const float4 va = ldsf4(I0 + (i + t + 1) * 24 + fc);
                const int ar = (i + t) * 24 + fc;
                const float4 vb = ldsf4(ST + ar);
                const float4 vc = ldsf4(ST + 528 + ar);
                const float4 vd = ldsf4(ST + 1056 + ar);
                fma4(s0, hk0[t], va); fma4(s0, gk0[t], vb);
                fma4(s1, hk1[t], va); fma4(s1, gk1[t], vb);
                fma4(d0, hk0[t], vc); fma4(d0, gk0[t], vd);
                fma4(d1, hk1[t], vc); fma4(d1, gk1[t], vd);
            }
            const int ri = 2 * i;
            stsf4(SD + ri * 24 + fc, s0); stsf4(SD + (ri + 1) * 24 + fc, s1);
            stsf4(SD + 864 + ri * 24 + fc, d0); stsf4(SD + 864 + (ri + 1) * 24 + fc, d1);
        }
        __syncthreads();
        {   // issue A0: 3 planes [36][40], 1080 f4 (overlaps horiz1)
            const int a0r0 = 32 * tr - 2, a0c0 = 32 * tc - 4;
#pragma unroll
            for (int k = 0; k < 5; ++k) {
                const int e = tid + 256 * k;
                if (e < 1080) {
                    const int q = e / 360, rm = e - q * 360, r = rm / 10, c4 = rm - r * 10;
                    const float* p = (q == 0) ? psd0 : (q == 1) ? pds0 : pdd0;
                    gl_lds16(p + (a0r0 + r) * 512 + a0c0 + 4 * c4, ST + 4 * e);
                }
            }
        }
        // horiz1 -> I1 x-grid (648 items)
        for (int e = tid; e < 648; e += 256) {
            const int ri = e / 18, pc = e - ri * 18;
            float o0 = 0.f, o1 = 0.f;
#pragma unroll
            for (int t = 0; t < TAPS; ++t) {
                const float sv = SD[ri * 24 + pc + 1 + t];
                const float dv = SD[864 + ri * 24 + pc + 1 + t];
                o0 += hk0[t] * sv + gk0[t] * dv;
                o1 += hk1[t] * sv + gk1[t] * dv;
            }
            I1[ri * 40 + 2 * pc + 2] = o0; I1[ri * 40 + 2 * pc + 3] = o1;
        }
        __syncthreads();   // drains A0 loads
    } else {
        // ======== EDGE PATH (R16 structure; A0/I1 on the x-grid) ========
        {   // stage A2 scalar
            const int r0g = (R0 >> 3) - 4, c0g = (W0 >> 3) - 4;
            for (int e = tid; e < 1024; e += 256) {
                const int q = e >> 8, rm = e & 255;
                const float* p = (q == 0) ? pss : (q == 1) ? psd2 : (q == 2) ? pds2 : pdd2;
                ST[e] = ldrc(p, r0g + (rm >> 4), c0g + (rm & 15), 128);
            }
        }
        __syncthreads();
        {   // vert2 (runtime bounds)
            const int lo = max((R0 >> 3) - 2, 0), hi = min((R0 >> 3) + 10, 128);
            const int a2r0 = (R0 >> 3) - 4;
            const int cnt = (hi - lo) * 4;
            for (int e = tid; e < cnt; e += 256) {
                const int i = e >> 2, fc = (e & 3) * 4;
                const int n = lo + i;
                float4 s0{0,0,0,0}, s1{0,0,0,0}, d0{0,0,0,0}, d1{0,0,0,0};
#pragma unroll
                for (int t = 0; t < TAPS; ++t) {
                    const int rr = (n - 2 + t - a2r0) * 16 + fc;
                    const float4 va = ldsf4(ST + rr);
                    const float4 vb = ldsf4(ST + 256 + rr);
                    const float4 vc = ldsf4(ST + 512 + rr);
                    const float4 vd = ldsf4(ST + 768 + rr);
                    fma4(s0, hk0[t], va); fma4(s0, gk0[t], vb);
                    fma4(s1, hk1[t], va); fma4(s1, gk1[t], vb);
                    fma4(d0, hk0[t], vc); fma4(d0, gk0[t], vd);
                    fma4(d1, hk1[t], vc); fma4(d1, gk1[t], vd);
                }
                const int ri = 2 * (n - ((R0 >> 3) - 2));
                stsf4(SD + ri * 16 + fc, s0); stsf4(SD + (ri + 1) * 16 + fc, s1);
                stsf4(SD + 384 + ri * 16 + fc, d0); stsf4(SD + 384 + (ri + 1) * 16 + fc, d1);
            }
        }
        __syncthreads();
        float rA1[7];
        {   // stage A1 -> regs
            const int a1r0 = (R0 >> 2) - 3, a1c0 = (W0 >> 2) - 4;
#pragma unroll
            for (int k = 0; k < 7; ++k) {
                const int e = tid + 256 * k;
                if (e < 1584) {
                    const int q = e / 528, rm = e - q * 528;
                    const float* p = (q == 0) ? psd1 : (q == 1) ? pds1 : pdd1;
                    rA1[k] = ldrc(p, a1r0 + rm / 24, a1c0 + rm % 24, 256);
                }
            }
        }
        {   // horiz2 (runtime bounds)
            const int i0r0 = (R0 >> 2) - 4;
            const int riLo = max(0, -i0r0), riHi = min(24, 256 - i0r0);
            const int pcLo = max(0, -((W0 >> 3) - 2)), pcHi = min(12, 128 - ((W0 >> 3) - 2));
            const int np = pcHi - pcLo, cnt = (riHi - riLo) * np;
            for (int e = tid; e < cnt; e += 256) {
                const int ri = riLo + e / np, pc = pcLo + e % np;
                float o0 = 0.f, o1 = 0.f;
#pragma unroll
                for (int t = 0; t < TAPS; ++t) {
                    const float sv = SD[ri * 16 + pc + t];
                    const float dv = SD[384 + ri * 16 + pc + t];
                    o0 += hk0[t] * sv + gk0[t] * dv;
                    o1 += hk1[t] * sv + gk1[t] * dv;
                }
                I0[ri * 24 + 2 * pc] = o0; I0[ri * 24 + 2 * pc + 1] = o1;
            }
        }
#pragma unroll
        for (int k = 0; k < 7; ++k) { const int e = tid + 256 * k; if (e < 1584) ST[e] = rA1[k]; }
        __syncthreads();
        {   // I0 col fixup
            const int i0r0 = (R0 >> 2) - 4, i0c0 = (W0 >> 2) - 4;
            const int riLo = max(0, -i0r0), riHi = min(24, 256 - i0r0), nr = riHi - riLo;
            const int zL = max(0, -i0c0), eR = min(24, 256 - i0c0);
            if (zL > 0) for (int e = tid; e < nr * zL; e += 256) {
                const int ri = riLo + e / zL, vc = e % zL;
                I0[ri * 24 + vc] = 2.f * I0[ri * 24 + zL] - I0[ri * 24 + 2 * zL - vc];
            }
            if (eR < 24) { const int nv = 24 - eR;
                for (int e = tid; e < nr * nv; e += 256) {
                    const int ri = riLo + e / nv, vc = eR + e % nv;
                    I0[ri * 24 + vc] = 2.f * I0[ri * 24 + eR - 1] - I0[ri * 24 + 2 * (eR - 1) - vc];
                } }
        }
        __syncthreads();
        {   // I0 row fixup
            const int i0r0 = (R0 >> 2) - 4;
            const int zT = max(0, -i0r0), eB = min(24, 256 - i0r0);
            if (zT > 0) for (int e = tid; e < zT * 24; e += 256) {
                const int vr = e / 24, c = e % 24;
                I0[vr * 24 + c] = 2.f * I0[zT * 24 + c] - I0[(2 * zT - vr) * 24 + c];
            }
            if (eB < 24) { const int nv = 24 - eB;
                for (int e = tid; e < nv * 24; e += 256) {
                    const int vr = eB + e / 24, c = e % 24;
                    I0[vr * 24 + c] = 2.f * I0[(eB - 1) * 24 + c] - I0[(2 * (eB - 1) - vr) * 24 + c];
                } }
        }
        __syncthreads();
        {   // vert1 (runtime bounds)
            const int lo = max((R0 >> 2) - 1, 0), hi = min((R0 >> 2) + 17, 256);
            const int i0r0 = (R0 >> 2) - 4, a1r0 = (R0 >> 2) - 3;
            const int cnt = (hi - lo) * 6;
            for (int e = tid; e < cnt; e += 256) {
                const int i = e / 6, fc = (e % 6) * 4;
                const int n = lo + i;
                float4 s0{0,0,0,0}, s1{0,0,0,0}, d0{0,0,0,0}, d1{0,0,0,0};
#pragma unroll
                for (int t = 0; t < TAPS; ++t) {
                    const int m = n - 2 + t;
                    const float4 va = ldsf4(I0 + (m - i0r0) * 24 + fc);
                    const int ar = (m - a1r0) * 24 + fc;
                    const float4 vb = ldsf4(ST + ar);
                    const float4 vc = ldsf4(ST + 528 + ar);
                    const float4 vd = ldsf4(ST + 1056 + ar);
                    fma4(s0, hk0[t], va); fma4(s0, gk0[t], vb);
                    fma4(s1, hk1[t], va); fma4(s1, gk1[t], vb);
                    fma4(d0, hk0[t], vc); fma4(d0, gk0[t], vd);
                    fma4(d1, hk1[t], vc); fma4(d1, gk1[t], vd);
                }
                const int ri = 2 * (n - ((R0 >> 2) - 1));
                stsf4(SD + ri * 24 + fc, s0); stsf4(SD + (ri + 1) * 24 + fc, s1);
                stsf4(SD + 864 + ri * 24 + fc, d0); stsf4(SD + 864 + (ri + 1) * 24 + fc, d1);
            }
        }
        __syncthreads();
        float rA0[17];
        {   // stage A0 -> regs ([3][36][40], x-grid)
            const int a0r0 = (R0 >> 1) - 2, a0c0 = (W0 >> 1) - 4;
#pragma unroll
            for (int k = 0; k < 17; ++k) {
                const int e = tid + 256 * k;
                if (e < 4320) {
                    const int q = e / 1440, rm = e - q * 1440;
                    const float* p = (q == 0) ? psd0 : (q == 1) ? pds0 : pdd0;
                    rA0[k] = ldrc(p, a0r0 + rm / 40, a0c0 + rm % 40, 512);
                }
            }
        }
        {   // horiz1 (runtime bounds, x-grid writes)
            const int i1r0 = (R0 >> 1) - 2;
            const int riLo = max(0, -i1r0), riHi = min(36, 512 - i1r0);
            const int pcLo = max(0, -((W0 >> 2) - 1)), pcHi = min(18, 256 - ((W0 >> 2) - 1));
            const int np = pcHi - pcLo, cnt = (riHi - riLo) * np;
            for (int e = tid; e < cnt; e += 256) {
                const int ri = riLo + e / np, pc = pcLo + e % np;
                float o0 = 0.f, o1 = 0.f;
#pragma unroll
                for (int t = 0; t < TAPS; ++t) {
                    const float sv = SD[ri * 24 + pc + 1 + t];
                    const float dv = SD[864 + ri * 24 + pc + 1 + t];
                    o0 += hk0[t] * sv + gk0[t] * dv;
                    o1 += hk1[t] * sv + gk1[t] * dv;
                }
                I1[ri * 40 + 2 * pc + 2] = o0; I1[ri * 40 + 2 * pc + 3] = o1;
            }
        }
#pragma unroll
        for (int k = 0; k < 17; ++k) { const int e = tid + 256 * k; if (e < 4320) ST[e] = rA0[k]; }
        __syncthreads();
        {   // I1 col fixup (window idx k in [0,36) <-> x = k+2)
            const int i1r0 = (R0 >> 1) - 2, c0t = (W0 >> 1) - 2;
            const int riLo = max(0, -i1r0), riHi = min(36, 512 - i1r0), nr = riHi - riLo;
            const int zL = max(0, -c0t), eR = min(36, 512 - c0t);
            if (zL > 0) for (int e = tid; e < nr * zL; e += 256) {
                const int ri = riLo + e / zL, x = e % zL + 2, zx = zL + 2;
                I1[ri * 40 + x] = 2.f * I1[ri * 40 + zx] - I1[ri * 40 + 2 * zx - x];
            }
            if (eR < 36) { const int nv = 36 - eR;
                for (int e = tid; e < nr * nv; e += 256) {
                    const int ri = riLo + e / nv, x = eR + e % nv + 2, ex = eR + 1;
                    I1[ri * 40 + x] = 2.f * I1[ri * 40 + ex] - I1[ri * 40 + 2 * ex - x];
                } }
        }
        __syncthreads();
        {   // I1 row fixup (cols x in [2,38))
            const int i1r0 = (R0 >> 1) - 2;
            const int zT = max(0, -i1r0), eB = min(36, 512 - i1r0);
            if (zT > 0) for (int e = tid; e < zT * 36; e += 256) {
                const int vr = e / 36, c = e % 36 + 2;
                I1[vr * 40 + c] = 2.f * I1[zT * 40 + c] - I1[(2 * zT - vr) * 40 + c];
            }
            if (eB < 36) { const int nv = 36 - eB;
                for (int e = tid; e < nv * 36; e += 256) {
                    const int vr = eB + e / 36, c = e % 36 + 2;
                    I1[vr * 40 + c] = 2.f * I1[(eB - 1) * 40 + c] - I1[(2 * (eB - 1) - vr) * 40 + c];
                } }
        }
        __syncthreads();
    }

    // ================= common LEVEL 0 =================
    // vert0 -> S0 [64][40] @SD, D0 @SD+2560 (320 items, x-grid)
    for (int e = tid; e < 320; e += 256) {
        const int i = e / 10, fc = (e - i * 10) * 4;
        float4 s0{0,0,0,0}, s1{0,0,0,0}, d0{0,0,0,0}, d1{0,0,0,0};
#pragma unroll
        for (int t = 0; t < TAPS; ++t) {
            const int rr = (i + t) * 40 + fc;
            const float4 va = ldsf4(I1 + rr);
            const float4 vb = ldsf4(ST + rr);
            const float4 vc = ldsf4(ST + 1440 + rr);
            const float4 vd = ldsf4(ST + 2880 + rr);
            fma4(s0, hk0[t], va); fma4(s0, gk0[t], vb);
            fma4(s1, hk1[t], va); fma4(s1, gk1[t], vb);
            fma4(d0, hk0[t], vc); fma4(d0, gk0[t], vd);
            fma4(d1, hk1[t], vc); fma4(d1, gk1[t], vd);
        }
        const int ri = 2 * i;
        stsf4(SD + ri * 40 + fc, s0); stsf4(SD + (ri + 1) * 40 + fc, s1);
        stsf4(SD + 2560 + ri * 40 + fc, d0); stsf4(SD + 2560 + (ri + 1) * 40 + fc, d1);
    }
    __syncthreads();
    // horiz0: 512 items; sv window x = 4u..4u+12, use [2+j+t]
    for (int e = tid; e < 512; e += 256) {
        const int ri = e >> 3, u = e & 7;
        float sv[12], dv[12];
        *reinterpret_cast<float4*>(&sv[0]) = ldsf4(SD + ri * 40 + 4 * u);
        *reinterpret_cast<float4*>(&sv[4]) = ldsf4(SD + ri * 40 + 4 * u + 4);
        *reinterpret_cast<float4*>(&sv[8]) = ldsf4(SD + ri * 40 + 4 * u + 8);
        *reinterpret_cast<float4*>(&dv[0]) = ldsf4(SD + 2560 + ri * 40 + 4 * u);
        *reinterpret_cast<float4*>(&dv[4]) = ldsf4(SD + 2560 + ri * 40 + 4 * u + 4);
        *reinterpret_cast<float4*>(&dv[8]) = ldsf4(SD + 2560 + ri * 40 + 4 * u + 8);
        float o[8];
#pragma unroll
        for (int j = 0; j < 4; ++j) {
            float o0 = 0.f, o1 = 0.f;
#pragma unroll
            for (int t = 0; t < TAPS; ++t) {
                o0 += hk0[t] * sv[2 + j + t] + gk0[t] * dv[2 + j + t];
                o1 += hk1[t] * sv[2 + j + t] + gk1[t] * dv[2 + j + t];
            }
            o[2 * j] = o0; o[2 * j + 1] = o1;
        }
        float* dst = out + ((size_t)(b * 1024 + R0 + ri)) * 1024 + W0 + 8 * u;
        *reinterpret_cast<float4*>(dst)     = make_float4(o[0], o[1], o[2], o[3]);
        *reinterpret_cast<float4*>(dst + 4) = make_float4(o[4], o[5], o[6], o[7]);
    }
}

extern "C" void kernel_launch(void* const* d_in, const int* in_sizes, int n_in,
                              void* d_out, int out_size, void* d_ws, size_t ws_size,
                              hipStream_t stream) {
    const float* ss  = (const float*)d_in[0];
    const float* sd0 = (const float*)d_in[1];
    const float* sd1 = (const float*)d_in[2];
    const float* sd2 = (const float*)d_in[3];
    const float* ds0 = (const float*)d_in[4];
    const float* ds1 = (const float*)d_in[5];
    const float* ds2 = (const float*)d_in[6];
    const float* dd0 = (const float*)d_in[7];
    const float* dd1 = (const float*)d_in[8];
    const float* dd2 = (const float*)d_in[9];
    const float* h = (const float*)d_in[10];
    const float* g = (const float*)d_in[11];
    float* out = (float*)d_out;

    idwt3<<<2048, 256, SM_FLOATS * 4, stream>>>(
        ss, sd0, sd1, sd2, ds0, ds1, ds2, dd0, dd1, dd2, h, g, out);
}

// Round 18
// 30.831 us; speedup vs baseline: 2.2015x; 1.2337x over previous
//
#include <hip/hip_runtime.h>

#define TAPS 5
#define BLK 512

// antireflect fetch from a global plane
__device__ __forceinline__ float ldcg(const float* __restrict__ row, int j, int N) {
    if ((unsigned)j < (unsigned)N) return row[j];
    const int e = (j < 0) ? 0 : N - 1;
    const int r = (j < 0) ? -j : 2 * (N - 1) - j;
    return 2.f * row[e] - row[r];
}
__device__ __forceinline__ float ldrc(const float* __restrict__ p, int m, int j, int N) {
    if ((unsigned)m < (unsigned)N) return ldcg(p + (size_t)m * N, j, N);
    const int e = (m < 0) ? 0 : N - 1;
    const int r = (m < 0) ? -m : 2 * (N - 1) - m;
    return 2.f * ldcg(p + (size_t)e * N, j, N) - ldcg(p + (size_t)r * N, j, N);
}
__device__ __forceinline__ void fma4(float4& a, float c, const float4& v) {
    a.x += c * v.x; a.y += c * v.y; a.z += c * v.z; a.w += c * v.w;
}
__device__ __forceinline__ float4 ldsf4(const float* p) { return *reinterpret_cast<const float4*>(p); }
__device__ __forceinline__ void stsf4(float* p, const float4& v) { *reinterpret_cast<float4*>(p) = v; }
__device__ __forceinline__ void gl_lds16(const float* g, float* l) {
    __builtin_amdgcn_global_load_lds(
        (const __attribute__((address_space(1))) void*)g,
        (__attribute__((address_space(3))) void*)l, 16, 0, 0);
}

// LDS floats: ST 0..4320 | SD 4320..9440 | I0 9440..10016 | I1 10016..11456
#define OFF_SD 4320
#define OFF_I0 9440
#define OFF_I1 10016
#define SM_FLOATS 11456

// One block (512 threads) = one 64x64 output tile; 3 IDWT levels fused in LDS.
__global__ __launch_bounds__(BLK)
void idwt3(const float* __restrict__ ss,
           const float* __restrict__ sd0, const float* __restrict__ sd1, const float* __restrict__ sd2,
           const float* __restrict__ ds0, const float* __restrict__ ds1, const float* __restrict__ ds2,
           const float* __restrict__ dd0, const float* __restrict__ dd1, const float* __restrict__ dd2,
           const float* __restrict__ h, const float* __restrict__ g_,
           float* __restrict__ out) {
    extern __shared__ float sm[];
    float* ST = sm;
    float* SD = sm + OFF_SD;
    float* I0 = sm + OFF_I0;   // [24][24], row0 = R0/4-4, col0 = W0/4-4
    float* I1 = sm + OFF_I1;   // [36][40], row0 = R0/2-2, x-grid col0 = W0/2-4

    const int hw = blockIdx.x;
    const int lb = (hw & 7) * 256 + (hw >> 3);   // XCD swizzle: XCD i -> batch i
    const int b  = lb >> 8;
    const int tile = lb & 255;
    const int tr = tile >> 4, tc = tile & 15;
    const int R0 = tr * 64, W0 = tc * 64;
    const int tid = threadIdx.x;

    float hk0[TAPS], hk1[TAPS], gk0[TAPS], gk1[TAPS];
#pragma unroll
    for (int t = 0; t < TAPS; ++t) {
        hk0[t] = h[8 - 2 * t];  hk1[t] = h[9 - 2 * t];
        gk0[t] = g_[8 - 2 * t]; gk1[t] = g_[9 - 2 * t];
    }

    const float* pss  = ss  + (size_t)b * 16384;
    const float* psd2 = sd2 + (size_t)b * 16384;
    const float* pds2 = ds2 + (size_t)b * 16384;
    const float* pdd2 = dd2 + (size_t)b * 16384;
    const float* psd1 = sd1 + (size_t)b * 65536;
    const float* pds1 = ds1 + (size_t)b * 65536;
    const float* pdd1 = dd1 + (size_t)b * 65536;
    const float* psd0 = sd0 + (size_t)b * 262144;
    const float* pds0 = ds0 + (size_t)b * 262144;
    const float* pdd0 = dd0 + (size_t)b * 262144;

    const bool inner = (tr >= 1) && (tr <= 14) && (tc >= 1) && (tc <= 14);

    if (inner) {
        // ======== FAST PATH ========
        if (tid < 256) {   // A2: 4 planes [16][16], 256 f4
            const int r0g = 8 * tr - 4, c0g = 8 * tc - 4;
            const int q = tid >> 6, rm = tid & 63, r = rm >> 2, c4 = rm & 3;
            const float* p = (q == 0) ? pss : (q == 1) ? psd2 : (q == 2) ? pds2 : pdd2;
            gl_lds16(p + (r0g + r) * 128 + c0g + 4 * c4, ST + 4 * tid);
        }
        __syncthreads();
        // vert2 -> S2 [24][16] @SD, D2 @SD+384
        if (tid < 48) {
            const int i = tid >> 2, fc = (tid & 3) * 4;
            float4 s0{0,0,0,0}, s1{0,0,0,0}, d0{0,0,0,0}, d1{0,0,0,0};
#pragma unroll
            for (int t = 0; t < TAPS; ++t) {
                const int rr = (i + t) * 16 + fc;
                const float4 va = ldsf4(ST + rr);
                const float4 vb = ldsf4(ST + 256 + rr);
                const float4 vc = ldsf4(ST + 512 + rr);
                const float4 vd = ldsf4(ST + 768 + rr);
                fma4(s0, hk0[t], va); fma4(s0, gk0[t], vb);
                fma4(s1, hk1[t], va); fma4(s1, gk1[t], vb);
                fma4(d0, hk0[t], vc); fma4(d0, gk0[t], vd);
                fma4(d1, hk1[t], vc); fma4(d1, gk1[t], vd);
            }
            const int ri = 2 * i;
            stsf4(SD + ri * 16 + fc, s0); stsf4(SD + (ri + 1) * 16 + fc, s1);
            stsf4(SD + 384 + ri * 16 + fc, d0); stsf4(SD + 384 + (ri + 1) * 16 + fc, d1);
        }
        __syncthreads();
        if (tid < 396) {   // issue A1: 3 planes [22][24], 396 f4 (overlaps horiz2)
            const int a1r0 = 16 * tr - 3, a1c0 = 16 * tc - 4;
            const int q = tid / 132, rm = tid - q * 132, r = rm / 6, c4 = rm - r * 6;
            const float* p = (q == 0) ? psd1 : (q == 1) ? pds1 : pdd1;
            gl_lds16(p + (a1r0 + r) * 256 + a1c0 + 4 * c4, ST + 4 * tid);
        }
        // horiz2 -> I0 [24][24] (288 items)
        if (tid < 288) {
            const int ri = tid / 12, pc = tid - ri * 12;
            float o0 = 0.f, o1 = 0.f;
#pragma unroll
            for (int t = 0; t < TAPS; ++t) {
                const float sv = SD[ri * 16 + pc + t];
                const float dv = SD[384 + ri * 16 + pc + t];
                o0 += hk0[t] * sv + gk0[t] * dv;
                o1 += hk1[t] * sv + gk1[t] * dv;
            }
            I0[ri * 24 + 2 * pc] = o0; I0[ri * 24 + 2 * pc + 1] = o1;
        }
        __syncthreads();   // drains A1 loads
        // vert1 -> S1 [36][24] @SD, D1 @SD+864 (108 items)
        if (tid < 108) {
            const int i = tid / 6, fc = (tid - i * 6) * 4;
            float4 s0{0,0,0,0}, s1{0,0,0,0}, d0{0,0,0,0}, d1{0,0,0,0};
#pragma unroll
            for (int t = 0; t < TAPS; ++t) {
                const float4 va = ldsf4(I0 + (i + t + 1) * 24 + fc);
                const int ar = (i + t) * 24 + fc;
                const float4 vb = ldsf4(ST + ar);
                const float4 vc = ldsf4(ST + 528 + ar);
                const float4 vd = ldsf4(ST + 1056 + ar);
                fma4(s0, hk0[t], va); fma4(s0, gk0[t], vb);
                fma4(s1, hk1[t], va); fma4(s1, gk1[t], vb);
                fma4(d0, hk0[t], vc); fma4(d0, gk0[t], vd);
                fma4(d1, hk1[t], vc); fma4(d1, gk1[t], vd);
            }
            const int ri = 2 * i;
            stsf4(SD + ri * 24 + fc, s0); stsf4(SD + (ri + 1) * 24 + fc, s1);
            stsf4(SD + 864 + ri * 24 + fc, d0); stsf4(SD + 864 + (ri + 1) * 24 + fc, d1);
        }
        __syncthreads();
        {   // issue A0: 3 planes [36][40], 1080 f4 (overlaps horiz1)
            const int a0r0 = 32 * tr - 2, a0c0 = 32 * tc - 4;
#pragma unroll
            for (int k = 0; k < 3; ++k) {
                const int e = tid + BLK * k;
                if (e < 1080) {
                    const int q = e / 360, rm = e - q * 360, r = rm / 10, c4 = rm - r * 10;
                    const float* p = (q == 0) ? psd0 : (q == 1) ? pds0 : pdd0;
                    gl_lds16(p + (a0r0 + r) * 512 + a0c0 + 4 * c4, ST + 4 * e);
                }
            }
        }
        // horiz1 -> I1 x-grid (648 items)
#pragma unroll
        for (int k = 0; k < 2; ++k) {
            const int e = tid + BLK * k;
            if (e < 648) {
                const int ri = e / 18, pc = e - ri * 18;
                float o0 = 0.f, o1 = 0.f;
#pragma unroll
                for (int t = 0; t < TAPS; ++t) {
                    const float sv = SD[ri * 24 + pc + 1 + t];
                    const float dv = SD[864 + ri * 24 + pc + 1 + t];
                    o0 += hk0[t] * sv + gk0[t] * dv;
                    o1 += hk1[t] * sv + gk1[t] * dv;
                }
                I1[ri * 40 + 2 * pc + 2] = o0; I1[ri * 40 + 2 * pc + 3] = o1;
            }
        }
        __syncthreads();   // drains A0 loads
    } else {
        // ======== EDGE PATH ========
        {   // stage A2 scalar
            const int r0g = (R0 >> 3) - 4, c0g = (W0 >> 3) - 4;
            for (int e = tid; e < 1024; e += BLK) {
                const int q = e >> 8, rm = e & 255;
                const float* p = (q == 0) ? pss : (q == 1) ? psd2 : (q == 2) ? pds2 : pdd2;
                ST[e] = ldrc(p, r0g + (rm >> 4), c0g + (rm & 15), 128);
            }
        }
        __syncthreads();
        {   // vert2 (runtime bounds)
            const int lo = max((R0 >> 3) - 2, 0), hi = min((R0 >> 3) + 10, 128);
            const int a2r0 = (R0 >> 3) - 4;
            const int cnt = (hi - lo) * 4;
            for (int e = tid; e < cnt; e += BLK) {
                const int i = e >> 2, fc = (e & 3) * 4;
                const int n = lo + i;
                float4 s0{0,0,0,0}, s1{0,0,0,0}, d0{0,0,0,0}, d1{0,0,0,0};
#pragma unroll
                for (int t = 0; t < TAPS; ++t) {
                    const int rr = (n - 2 + t - a2r0) * 16 + fc;
                    const float4 va = ldsf4(ST + rr);
                    const float4 vb = ldsf4(ST + 256 + rr);
                    const float4 vc = ldsf4(ST + 512 + rr);
                    const float4 vd = ldsf4(ST + 768 + rr);
                    fma4(s0, hk0[t], va); fma4(s0, gk0[t], vb);
                    fma4(s1, hk1[t], va); fma4(s1, gk1[t], vb);
                    fma4(d0, hk0[t], vc); fma4(d0, gk0[t], vd);
                    fma4(d1, hk1[t], vc); fma4(d1, gk1[t], vd);
                }
                const int ri = 2 * (n - ((R0 >> 3) - 2));
                stsf4(SD + ri * 16 + fc, s0); stsf4(SD + (ri + 1) * 16 + fc, s1);
                stsf4(SD + 384 + ri * 16 + fc, d0); stsf4(SD + 384 + (ri + 1) * 16 + fc, d1);
            }
        }
        __syncthreads();
        float rA1[4];
        {   // stage A1 -> regs
            const int a1r0 = (R0 >> 2) - 3, a1c0 = (W0 >> 2) - 4;
#pragma unroll
            for (int k = 0; k < 4; ++k) {
                const int e = tid + BLK * k;
                if (e < 1584) {
                    const int q = e / 528, rm = e - q * 528;
                    const float* p = (q == 0) ? psd1 : (q == 1) ? pds1 : pdd1;
                    rA1[k] = ldrc(p, a1r0 + rm / 24, a1c0 + rm % 24, 256);
                }
            }
        }
        {   // horiz2 (runtime bounds)
            const int i0r0 = (R0 >> 2) - 4;
            const int riLo = max(0, -i0r0), riHi = min(24, 256 - i0r0);
            const int pcLo = max(0, -((W0 >> 3) - 2)), pcHi = min(12, 128 - ((W0 >> 3) - 2));
            const int np = pcHi - pcLo, cnt = (riHi - riLo) * np;
            for (int e = tid; e < cnt; e += BLK) {
                const int ri = riLo + e / np, pc = pcLo + e % np;
                float o0 = 0.f, o1 = 0.f;
#pragma unroll
                for (int t = 0; t < TAPS; ++t) {
                    const float sv = SD[ri * 16 + pc + t];
                    const float dv = SD[384 + ri * 16 + pc + t];
                    o0 += hk0[t] * sv + gk0[t] * dv;
                    o1 += hk1[t] * sv + gk1[t] * dv;
                }
                I0[ri * 24 + 2 * pc] = o0; I0[ri * 24 + 2 * pc + 1] = o1;
            }
        }
#pragma unroll
        for (int k = 0; k < 4; ++k) { const int e = tid + BLK * k; if (e < 1584) ST[e] = rA1[k]; }
        __syncthreads();
        {   // I0 col fixup
            const int i0r0 = (R0 >> 2) - 4, i0c0 = (W0 >> 2) - 4;
            const int riLo = max(0, -i0r0), riHi = min(24, 256 - i0r0), nr = riHi - riLo;
            const int zL = max(0, -i0c0), eR = min(24, 256 - i0c0);
            if (zL > 0) for (int e = tid; e < nr * zL; e += BLK) {
                const int ri = riLo + e / zL, vc = e % zL;
                I0[ri * 24 + vc] = 2.f * I0[ri * 24 + zL] - I0[ri * 24 + 2 * zL - vc];
            }
            if (eR < 24) { const int nv = 24 - eR;
                for (int e = tid; e < nr * nv; e += BLK) {
                    const int ri = riLo + e / nv, vc = eR + e % nv;
                    I0[ri * 24 + vc] = 2.f * I0[ri * 24 + eR - 1] - I0[ri * 24 + 2 * (eR - 1) - vc];
                } }
        }
        __syncthreads();
        {   // I0 row fixup
            const int i0r0 = (R0 >> 2) - 4;
            const int zT = max(0, -i0r0), eB = min(24, 256 - i0r0);
            if (zT > 0) for (int e = tid; e < zT * 24; e += BLK) {
                const int vr = e / 24, c = e % 24;
                I0[vr * 24 + c] = 2.f * I0[zT * 24 + c] - I0[(2 * zT - vr) * 24 + c];
            }
            if (eB < 24) { const int nv = 24 - eB;
                for (int e = tid; e < nv * 24; e += BLK) {
                    const int vr = eB + e / 24, c = e % 24;
                    I0[vr * 24 + c] = 2.f * I0[(eB - 1) * 24 + c] - I0[(2 * (eB - 1) - vr) * 24 + c];
                } }
        }
        __syncthreads();
        {   // vert1 (runtime bounds)
            const int lo = max((R0 >> 2) - 1, 0), hi = min((R0 >> 2) + 17, 256);
            const int i0r0 = (R0 >> 2) - 4, a1r0 = (R0 >> 2) - 3;
            const int cnt = (hi - lo) * 6;
            for (int e = tid; e < cnt; e += BLK) {
                const int i = e / 6, fc = (e % 6) * 4;
                const int n = lo + i;
                float4 s0{0,0,0,0}, s1{0,0,0,0}, d0{0,0,0,0}, d1{0,0,0,0};
#pragma unroll
                for (int t = 0; t < TAPS; ++t) {
                    const int m = n - 2 + t;
                    const float4 va = ldsf4(I0 + (m - i0r0) * 24 + fc);
                    const int ar = (m - a1r0) * 24 + fc;
                    const float4 vb = ldsf4(ST + ar);
                    const float4 vc = ldsf4(ST + 528 + ar);
                    const float4 vd = ldsf4(ST + 1056 + ar);
                    fma4(s0, hk0[t], va); fma4(s0, gk0[t], vb);
                    fma4(s1, hk1[t], va); fma4(s1, gk1[t], vb);
                    fma4(d0, hk0[t], vc); fma4(d0, gk0[t], vd);
                    fma4(d1, hk1[t], vc); fma4(d1, gk1[t], vd);
                }
                const int ri = 2 * (n - ((R0 >> 2) - 1));
                stsf4(SD + ri * 24 + fc, s0); stsf4(SD + (ri + 1) * 24 + fc, s1);
                stsf4(SD + 864 + ri * 24 + fc, d0); stsf4(SD + 864 + (ri + 1) * 24 + fc, d1);
            }
        }
        __syncthreads();
        float rA0[9];
        {   // stage A0 -> regs ([3][36][40], x-grid)
            const int a0r0 = (R0 >> 1) - 2, a0c0 = (W0 >> 1) - 4;
#pragma unroll
            for (int k = 0; k < 9; ++k) {
                const int e = tid + BLK * k;
                if (e < 4320) {
                    const int q = e / 1440, rm = e - q * 1440;
                    const float* p = (q == 0) ? psd0 : (q == 1) ? pds0 : pdd0;
                    rA0[k] = ldrc(p, a0r0 + rm / 40, a0c0 + rm % 40, 512);
                }
            }
        }
        {   // horiz1 (runtime bounds, x-grid writes)
            const int i1r0 = (R0 >> 1) - 2;
            const int riLo = max(0, -i1r0), riHi = min(36, 512 - i1r0);
            const int pcLo = max(0, -((W0 >> 2) - 1)), pcHi = min(18, 256 - ((W0 >> 2) - 1));
            const int np = pcHi - pcLo, cnt = (riHi - riLo) * np;
            for (int e = tid; e < cnt; e += BLK) {
                const int ri = riLo + e / np, pc = pcLo + e % np;
                float o0 = 0.f, o1 = 0.f;
#pragma unroll
                for (int t = 0; t < TAPS; ++t) {
                    const float sv = SD[ri * 24 + pc + 1 + t];
                    const float dv = SD[864 + ri * 24 + pc + 1 + t];
                    o0 += hk0[t] * sv + gk0[t] * dv;
                    o1 += hk1[t] * sv + gk1[t] * dv;
                }
                I1[ri * 40 + 2 * pc + 2] = o0; I1[ri * 40 + 2 * pc + 3] = o1;
            }
        }
#pragma unroll
        for (int k = 0; k < 9; ++k) {
            const int e = tid + BLK * k;
            if (e < 4320) ST[e] = rA0[k];
        }
        __syncthreads();
        {   // I1 col fixup (x = window k + 2)
            const int i1r0 = (R0 >> 1) - 2, c0t = (W0 >> 1) - 2;
            const int riLo = max(0, -i1r0), riHi = min(36, 512 - i1r0), nr = riHi - riLo;
            const int zL = max(0, -c0t), eR = min(36, 512 - c0t);
            if (zL > 0) for (int e = tid; e < nr * zL; e += BLK) {
                const int ri = riLo + e / zL, x = e % zL + 2, zx = zL + 2;
                I1[ri * 40 + x] = 2.f * I1[ri * 40 + zx] - I1[ri * 40 + 2 * zx - x];
            }
            if (eR < 36) { const int nv = 36 - eR;
                for (int e = tid; e < nr * nv; e += BLK) {
                    const int ri = riLo + e / nv, x = eR + e % nv + 2, ex = eR + 1;
                    I1[ri * 40 + x] = 2.f * I1[ri * 40 + ex] - I1[ri * 40 + 2 * ex - x];
                } }
        }
        __syncthreads();
        {   // I1 row fixup (cols x in [2,38))
            const int i1r0 = (R0 >> 1) - 2;
            const int zT = max(0, -i1r0), eB = min(36, 512 - i1r0);
            if (zT > 0) for (int e = tid; e < zT * 36; e += BLK) {
                const int vr = e / 36, c = e % 36 + 2;
                I1[vr * 40 + c] = 2.f * I1[zT * 40 + c] - I1[(2 * zT - vr) * 40 + c];
            }
            if (eB < 36) { const int nv = 36 - eB;
                for (int e = tid; e < nv * 36; e += BLK) {
                    const int vr = eB + e / 36, c = e % 36 + 2;
                    I1[vr * 40 + c] = 2.f * I1[(eB - 1) * 40 + c] - I1[(2 * (eB - 1) - vr) * 40 + c];
                } }
        }
        __syncthreads();
    }

    // ================= common LEVEL 0 =================
    // vert0 -> S0 [64][40] @SD, D0 @SD+2560 (320 items)
    if (tid < 320) {
        const int i = tid / 10, fc = (tid - i * 10) * 4;
        float4 s0{0,0,0,0}, s1{0,0,0,0}, d0{0,0,0,0}, d1{0,0,0,0};
#pragma unroll
        for (int t = 0; t < TAPS; ++t) {
            const int rr = (i + t) * 40 + fc;
            const float4 va = ldsf4(I1 + rr);
            const float4 vb = ldsf4(ST + rr);
            const float4 vc = ldsf4(ST + 1440 + rr);
            const float4 vd = ldsf4(ST + 2880 + rr);
            fma4(s0, hk0[t], va); fma4(s0, gk0[t], vb);
            fma4(s1, hk1[t], va); fma4(s1, gk1[t], vb);
            fma4(d0, hk0[t], vc); fma4(d0, gk0[t], vd);
            fma4(d1, hk1[t], vc); fma4(d1, gk1[t], vd);
        }
        const int ri = 2 * i;
        stsf4(SD + ri * 40 + fc, s0); stsf4(SD + (ri + 1) * 40 + fc, s1);
        stsf4(SD + 2560 + ri * 40 + fc, d0); stsf4(SD + 2560 + (ri + 1) * 40 + fc, d1);
    }
    __syncthreads();
    // horiz0: exactly 1 item per thread (512 items)
    {
        const int ri = tid >> 3, u = tid & 7;
        float sv[12], dv[12];
        *reinterpret_cast<float4*>(&sv[0]) = ldsf4(SD + ri * 40 + 4 * u);
        *reinterpret_cast<float4*>(&sv[4]) = ldsf4(SD + ri * 40 + 4 * u + 4);
        *reinterpret_cast<float4*>(&sv[8]) = ldsf4(SD + ri * 40 + 4 * u + 8);
        *reinterpret_cast<float4*>(&dv[0]) = ldsf4(SD + 2560 + ri * 40 + 4 * u);
        *reinterpret_cast<float4*>(&dv[4]) = ldsf4(SD + 2560 + ri * 40 + 4 * u + 4);
        *reinterpret_cast<float4*>(&dv[8]) = ldsf4(SD + 2560 + ri * 40 + 4 * u + 8);
        float o[8];
#pragma unroll
        for (int j = 0; j < 4; ++j) {
            float o0 = 0.f, o1 = 0.f;
#pragma unroll
            for (int t = 0; t < TAPS; ++t) {
                o0 += hk0[t] * sv[2 + j + t] + gk0[t] * dv[2 + j + t];
                o1 += hk1[t] * sv[2 + j + t] + gk1[t] * dv[2 + j + t];
            }
            o[2 * j] = o0; o[2 * j + 1] = o1;
        }
        float* dst = out + ((size_t)(b * 1024 + R0 + ri)) * 1024 + W0 + 8 * u;
        *reinterpret_cast<float4*>(dst)     = make_float4(o[0], o[1], o[2], o[3]);
        *reinterpret_cast<float4*>(dst + 4) = make_float4(o[4], o[5], o[6], o[7]);
    }
}

extern "C" void kernel_launch(void* const* d_in, const int* in_sizes, int n_in,
                              void* d_out, int out_size, void* d_ws, size_t ws_size,
                              hipStream_t stream) {
    const float* ss  = (const float*)d_in[0];
    const float* sd0 = (const float*)d_in[1];
    const float* sd1 = (const float*)d_in[2];
    const float* sd2 = (const float*)d_in[3];
    const float* ds0 = (const float*)d_in[4];
    const float* ds1 = (const float*)d_in[5];
    const float* ds2 = (const float*)d_in[6];
    const float* dd0 = (const float*)d_in[7];
    const float* dd1 = (const float*)d_in[8];
    const float* dd2 = (const float*)d_in[9];
    const float* h = (const float*)d_in[10];
    const float* g = (const float*)d_in[11];
    float* out = (float*)d_out;

    idwt3<<<2048, BLK, SM_FLOATS * 4, stream>>>(
        ss, sd0, sd1, sd2, ds0, ds1, ds2, dd0, dd1, dd2, h, g, out);
}